// Round 2
// baseline (1327.935 us; speedup 1.0000x reference)
//
#include <hip/hip_runtime.h>
#include <hip/hip_bf16.h>
#include <stdint.h>

// MoE top-1: gate -> group by expert -> grouped bf16-MFMA GEMMs (m97 structure).
#define N_TOK 4096
#define DIM   768
#define NE    8
#define HDIM  7680
#define ODIM  768

typedef __bf16 bf16x8 __attribute__((ext_vector_type(8)));
typedef float f32x4 __attribute__((ext_vector_type(4)));

__device__ __forceinline__ unsigned short f2bf(float f) {
    union { float f; unsigned u; } v; v.f = f;
    return (unsigned short)((v.u + 0x7fffu + ((v.u >> 16) & 1u)) >> 16);
}

// packed f32x2 -> bf16x2 (RNE), 1 instr for 2 elements
__device__ __forceinline__ unsigned cvt_pk_bf16(float lo, float hi) {
    unsigned r;
    asm("v_cvt_pk_bf16_f32 %0, %1, %2" : "=v"(r) : "v"(lo), "v"(hi));
    return r;
}

// async global->LDS, 16B per lane; LDS dest = wave-uniform base + lane*16
__device__ __forceinline__ void gload_lds16(const unsigned short* g, unsigned short* l) {
    __builtin_amdgcn_global_load_lds(
        (const __attribute__((address_space(1))) unsigned int*)g,
        (__attribute__((address_space(3))) unsigned int*)l, 16, 0, 0);
}

// ---------------- gating (unchanged from round 1, passed) ----------------
__global__ void moe_gating(const float* __restrict__ x, const float* __restrict__ Wg,
                           const float* __restrict__ bg, int* __restrict__ cnt,
                           int* __restrict__ top_e, int* __restrict__ rnk,
                           float* __restrict__ top_p) {
    const int wid  = threadIdx.x >> 6;
    const int lane = threadIdx.x & 63;
    const int t = blockIdx.x * 4 + wid;
    double p[NE];
#pragma unroll
    for (int j = 0; j < NE; ++j) p[j] = 0.0;
    const float* xr  = x  + (size_t)t * DIM + lane * 12;
    const float* wr0 = Wg + lane * 12 * NE;
#pragma unroll
    for (int i = 0; i < 12; ++i) {
        double xv = (double)xr[i];
#pragma unroll
        for (int j = 0; j < NE; ++j) p[j] += xv * (double)wr0[i * NE + j];
    }
#pragma unroll
    for (int off = 32; off >= 1; off >>= 1)
#pragma unroll
        for (int j = 0; j < NE; ++j) p[j] += __shfl_xor(p[j], off, 64);
    if (lane == 0) {
        double l[NE];
#pragma unroll
        for (int j = 0; j < NE; ++j) l[j] = p[j] + (double)bg[j];
        int be = 0; double bl = l[0];
#pragma unroll
        for (int j = 1; j < NE; ++j) if (l[j] > bl) { bl = l[j]; be = j; }
        double s = 0.0;
#pragma unroll
        for (int j = 0; j < NE; ++j) s += exp(l[j] - bl);
        int rk = atomicAdd(&cnt[be], 1);
        top_e[t] = be; rnk[t] = rk; top_p[t] = (float)(1.0 / s);
    }
}

__global__ void moe_init(int* cnt) { if (threadIdx.x < NE) cnt[threadIdx.x] = 0; }

__global__ void moe_scan(const int* __restrict__ cnt, int* __restrict__ offs) {
    if (threadIdx.x == 0) { int s = 0; for (int e = 0; e < NE; ++e) { offs[e] = s; s += cnt[e]; } }
}

__global__ void moe_mkperm(const int* __restrict__ top_e, const int* __restrict__ rnk,
                           const float* __restrict__ top_p, const int* __restrict__ offs,
                           int* __restrict__ perm, float* __restrict__ gate_s) {
    int t = blockIdx.x * 256 + threadIdx.x;
    int e = top_e[t];
    int slot = offs[e] + rnk[t];
    perm[slot] = t;
    gate_s[slot] = top_p[t];
}

__global__ void moe_gather(const float* __restrict__ x, const int* __restrict__ perm,
                           unsigned short* __restrict__ Xg) {
    int slot = blockIdx.x;
    int t = perm[slot];
    const float* src = x + (size_t)t * DIM;
    unsigned short* dst = Xg + (size_t)slot * DIM;
    for (int i = threadIdx.x; i < DIM; i += 256) dst[i] = f2bf(src[i]);
}

// out[t] = gate(t) * b2[e(t)]  (bias+gate seed; GEMM2 atomically adds gate*partials)
__global__ void moe_initout(const int* __restrict__ top_e, const float* __restrict__ top_p,
                            const float* __restrict__ b2, float* __restrict__ out) {
    int t = blockIdx.x;
    int e = top_e[t];
    float gv = top_p[t];
    const float* b = b2 + (size_t)e * ODIM;
    float* o = out + (size_t)t * ODIM;
    for (int i = threadIdx.x; i < ODIM; i += 256) o[i] = gv * b[i];
}

// ---------------- grouped GEMM ----------------
// 128x128 tile, BK=32, 4 waves (2x2), wave tile 64x64 = 4x4 frags of 16x16x32.
// A: global_load_lds into linear [128][32] with source chunk-swizzle c^=((row>>1)&3)
//    -> conflict-free b128 frag reads.
// B: fp32 loads -> cvt_pk bf16 -> n-major LDS [128][40] (16B-aligned stride)
//    -> b128 frag reads, ~2-way conflicts.
// LAYER==2 uses split-K x4 (blockIdx.z = e*4+ks), atomicAdd gate*partial into out.
template<int LAYER>
__global__ __launch_bounds__(256, 3) void moe_gemm(
    const unsigned short* __restrict__ A, const float* __restrict__ B,
    const float* __restrict__ bias, const int* __restrict__ cnt,
    const int* __restrict__ offs, const int* __restrict__ perm,
    const float* __restrict__ gate_s, unsigned short* __restrict__ H,
    float* __restrict__ out) {

    constexpr int NT    = (LAYER == 1) ? HDIM : ODIM;     // B cols
    constexpr int AST   = (LAYER == 1) ? DIM  : HDIM;     // A row stride
    constexpr int KFULL = (LAYER == 1) ? DIM  : HDIM;     // B rows per expert
    constexpr int KBLK  = (LAYER == 1) ? DIM  : HDIM / 4; // K extent per block

    const int e  = (LAYER == 1) ? blockIdx.z : (blockIdx.z >> 2);
    const int ks = (LAYER == 1) ? 0 : (blockIdx.z & 3);
    const int ne = cnt[e];
    const int mt = blockIdx.x;
    if (mt * 128 >= ne) return;
    const int base = offs[e];
    const int n0 = blockIdx.y * 128;
    const int mlim = ne - mt * 128;
    const int kbase = ks * KBLK;

    __shared__ unsigned short As[128 * 32];   // linear, chunk-swizzled
    __shared__ unsigned short Bs[128 * 40];   // n-major, stride 40 ushorts (80B)

    const int tid = threadIdx.x;
    const int lane = tid & 63, w = tid >> 6;
    const int wr = w >> 1, wc = w & 1;
    const int g = lane >> 4, r = lane & 15;

    // A staging: each wave DMA-loads 2x 16 rows (1KB each)
    const int tr0 = w * 32 + (lane >> 2);
    const int tr1 = tr0 + 16;
    const int ac  = (lane & 3) ^ ((tr0 >> 1) & 3);   // (tr1>>1)&3 == (tr0>>1)&3
    const int gr0 = base + mt * 128 + (tr0 < mlim ? tr0 : mlim - 1);
    const int gr1 = base + mt * 128 + (tr1 < mlim ? tr1 : mlim - 1);
    const unsigned short* aS0 = A + (size_t)gr0 * AST + kbase + ac * 8;
    const unsigned short* aS1 = A + (size_t)gr1 * AST + kbase + ac * 8;
    unsigned short* aD0 = &As[w * 1024];
    unsigned short* aD1 = &As[w * 1024 + 512];

    // B staging: thread owns column bn, 16 k-rows
    const int bn  = tid & 127;
    const int bkh = (tid >> 7) * 16;
    const float* bS = B + (size_t)e * KFULL * NT + (size_t)(kbase + bkh) * NT + n0 + bn;
    unsigned short* bD = &Bs[bn * 40 + bkh];

    const int acidx = g ^ ((r >> 1) & 3);   // A frag read swizzle

    f32x4 acc[4][4] = {};

    for (int k0 = 0; k0 < KBLK; k0 += 32) {
        __syncthreads();                         // prev compute done with LDS
        gload_lds16(aS0 + k0, aD0);
        gload_lds16(aS1 + k0, aD1);
        {
            float bv[16];
            const float* bp = bS + (size_t)k0 * NT;
#pragma unroll
            for (int i = 0; i < 16; ++i) bv[i] = bp[(size_t)i * NT];
            uint4 q0, q1;
            q0.x = cvt_pk_bf16(bv[0],  bv[1]);  q0.y = cvt_pk_bf16(bv[2],  bv[3]);
            q0.z = cvt_pk_bf16(bv[4],  bv[5]);  q0.w = cvt_pk_bf16(bv[6],  bv[7]);
            q1.x = cvt_pk_bf16(bv[8],  bv[9]);  q1.y = cvt_pk_bf16(bv[10], bv[11]);
            q1.z = cvt_pk_bf16(bv[12], bv[13]); q1.w = cvt_pk_bf16(bv[14], bv[15]);
            *(uint4*)bD       = q0;
            *(uint4*)(bD + 8) = q1;
        }
        __syncthreads();                         // staging (incl. DMA) visible

        bf16x8 af[4], bf[4];
#pragma unroll
        for (int m = 0; m < 4; ++m)
            af[m] = *(const bf16x8*)&As[(wr * 64 + m * 16 + r) * 32 + acidx * 8];
#pragma unroll
        for (int n = 0; n < 4; ++n)
            bf[n] = *(const bf16x8*)&Bs[(wc * 64 + n * 16 + r) * 40 + g * 8];
#pragma unroll
        for (int n = 0; n < 4; ++n)
#pragma unroll
            for (int m = 0; m < 4; ++m)
                acc[m][n] = __builtin_amdgcn_mfma_f32_16x16x32_bf16(af[m], bf[n], acc[m][n], 0, 0, 0);
    }

    // epilogue: C/D layout col = lane&15, row = 4*(lane>>4) + reg
#pragma unroll
    for (int m = 0; m < 4; ++m) {
#pragma unroll
        for (int j = 0; j < 4; ++j) {
            int lrow = mt * 128 + wr * 64 + m * 16 + g * 4 + j;
            if (lrow < ne) {
                int slot = base + lrow;
#pragma unroll
                for (int n = 0; n < 4; ++n) {
                    int col = n0 + wc * 64 + n * 16 + r;
                    if constexpr (LAYER == 1) {
                        float v = acc[m][n][j] + bias[(size_t)e * NT + col];
                        v = fmaxf(v, 0.0f);
                        H[(size_t)slot * HDIM + col] = f2bf(v);
                    } else {
                        atomicAdd(&out[(size_t)perm[slot] * ODIM + col],
                                  gate_s[slot] * acc[m][n][j]);
                    }
                }
            }
        }
    }
}

// ---------------- launch ----------------
extern "C" void kernel_launch(void* const* d_in, const int* in_sizes, int n_in,
                              void* d_out, int out_size, void* d_ws, size_t ws_size,
                              hipStream_t stream) {
    const float* x  = (const float*)d_in[0];
    const float* Wg = (const float*)d_in[1];
    const float* bg = (const float*)d_in[2];
    const float* W1 = (const float*)d_in[3];
    const float* b1 = (const float*)d_in[4];
    const float* W2 = (const float*)d_in[5];
    const float* b2 = (const float*)d_in[6];
    float* out = (float*)d_out;

    char* ws = (char*)d_ws;
    int*   cnt    = (int*)(ws + 0);
    int*   offs   = (int*)(ws + 64);
    int*   top_e  = (int*)(ws + 128);
    int*   rnk    = (int*)(ws + 128 + 16384);
    float* top_p  = (float*)(ws + 128 + 2 * 16384);
    int*   perm   = (int*)(ws + 128 + 3 * 16384);
    float* gate_s = (float*)(ws + 128 + 4 * 16384);
    unsigned short* Xg = (unsigned short*)(ws + 82048);                           // 4096x768 bf16
    unsigned short* H  = (unsigned short*)(ws + 82048 + (size_t)N_TOK * DIM * 2); // 4096x7680 bf16

    moe_init<<<1, 64, 0, stream>>>(cnt);
    moe_gating<<<N_TOK / 4, 256, 0, stream>>>(x, Wg, bg, cnt, top_e, rnk, top_p);
    moe_scan<<<1, 64, 0, stream>>>(cnt, offs);
    moe_mkperm<<<N_TOK / 256, 256, 0, stream>>>(top_e, rnk, top_p, offs, perm, gate_s);
    moe_gather<<<N_TOK, 256, 0, stream>>>(x, perm, Xg);
    moe_initout<<<N_TOK, 256, 0, stream>>>(top_e, top_p, b2, out);

    // grid: x = m-tiles (fastest -> weight-panel reuse in L2), y = n-tiles, z = expert[*split]
    moe_gemm<1><<<dim3(32, HDIM / 128, NE), 256, 0, stream>>>(
        Xg, W1, b1, cnt, offs, perm, gate_s, H, out);
    moe_gemm<2><<<dim3(32, ODIM / 128, NE * 4), 256, 0, stream>>>(
        H, W2, b2, cnt, offs, perm, gate_s, H, out);
}

// Round 3
// 412.366 us; speedup vs baseline: 3.2203x; 3.2203x over previous
//
#include <hip/hip_runtime.h>
#include <hip/hip_bf16.h>
#include <stdint.h>

// MoE top-1: gate -> group by expert -> tile table -> double-buffered grouped
// bf16-MFMA GEMMs with DMA A-staging and reg-staged B (fp32->bf16).
#define N_TOK 4096
#define DIM   768
#define NE    8
#define HDIM  7680
#define ODIM  768
#define MAXTILES 40

typedef __bf16 bf16x8 __attribute__((ext_vector_type(8)));
typedef float f32x4 __attribute__((ext_vector_type(4)));

__device__ __forceinline__ unsigned short f2bf(float f) {
    union { float f; unsigned u; } v; v.f = f;
    return (unsigned short)((v.u + 0x7fffu + ((v.u >> 16) & 1u)) >> 16);
}

__device__ __forceinline__ unsigned cvt_pk_bf16(float lo, float hi) {
    unsigned r;
    asm("v_cvt_pk_bf16_f32 %0, %1, %2" : "=v"(r) : "v"(lo), "v"(hi));
    return r;
}

// async global->LDS, 16B/lane; LDS dest = wave-uniform base + lane*16
__device__ __forceinline__ void gload_lds16(const unsigned short* g, unsigned short* l) {
    __builtin_amdgcn_global_load_lds(
        (const __attribute__((address_space(1))) unsigned int*)g,
        (__attribute__((address_space(3))) unsigned int*)l, 16, 0, 0);
}

// ---------------- gating (unchanged; validated rounds 1-2) ----------------
__global__ void moe_gating(const float* __restrict__ x, const float* __restrict__ Wg,
                           const float* __restrict__ bg, int* __restrict__ cnt,
                           int* __restrict__ top_e, int* __restrict__ rnk,
                           float* __restrict__ top_p) {
    const int wid  = threadIdx.x >> 6;
    const int lane = threadIdx.x & 63;
    const int t = blockIdx.x * 4 + wid;
    double p[NE];
#pragma unroll
    for (int j = 0; j < NE; ++j) p[j] = 0.0;
    const float* xr  = x  + (size_t)t * DIM + lane * 12;
    const float* wr0 = Wg + lane * 12 * NE;
#pragma unroll
    for (int i = 0; i < 12; ++i) {
        double xv = (double)xr[i];
#pragma unroll
        for (int j = 0; j < NE; ++j) p[j] += xv * (double)wr0[i * NE + j];
    }
#pragma unroll
    for (int off = 32; off >= 1; off >>= 1)
#pragma unroll
        for (int j = 0; j < NE; ++j) p[j] += __shfl_xor(p[j], off, 64);
    if (lane == 0) {
        double l[NE];
#pragma unroll
        for (int j = 0; j < NE; ++j) l[j] = p[j] + (double)bg[j];
        int be = 0; double bl = l[0];
#pragma unroll
        for (int j = 1; j < NE; ++j) if (l[j] > bl) { bl = l[j]; be = j; }
        double s = 0.0;
#pragma unroll
        for (int j = 0; j < NE; ++j) s += exp(l[j] - bl);
        int rk = atomicAdd(&cnt[be], 1);
        top_e[t] = be; rnk[t] = rk; top_p[t] = (float)(1.0 / s);
    }
}

__global__ void moe_init(int* cnt) { if (threadIdx.x < NE) cnt[threadIdx.x] = 0; }

// prefix sums + tile table (<= 39 entries of (e<<8)|mt)
__global__ void moe_scan(const int* __restrict__ cnt, int* __restrict__ offs,
                         int* __restrict__ tbl, int* __restrict__ ntt) {
    if (threadIdx.x == 0) {
        int s = 0, nt = 0;
        for (int e = 0; e < NE; ++e) {
            offs[e] = s;
            int m = (cnt[e] + 127) >> 7;
            for (int i = 0; i < m; ++i) tbl[nt++] = (e << 8) | i;
            s += cnt[e];
        }
        ntt[0] = nt;
    }
}

__global__ void moe_mkperm(const int* __restrict__ top_e, const int* __restrict__ rnk,
                           const float* __restrict__ top_p, const int* __restrict__ offs,
                           int* __restrict__ perm, float* __restrict__ gate_s) {
    int t = blockIdx.x * 256 + threadIdx.x;
    int e = top_e[t];
    int slot = offs[e] + rnk[t];
    perm[slot] = t;
    gate_s[slot] = top_p[t];
}

__global__ void moe_gather(const float* __restrict__ x, const int* __restrict__ perm,
                           unsigned short* __restrict__ Xg) {
    int slot = blockIdx.x;
    int t = perm[slot];
    const float* src = x + (size_t)t * DIM;
    unsigned short* dst = Xg + (size_t)slot * DIM;
    for (int i = threadIdx.x; i < DIM; i += 256) dst[i] = f2bf(src[i]);
}

// out[t] = gate(t) * b2[e(t)] ; GEMM2 atomically adds gate*partials
__global__ void moe_initout(const int* __restrict__ top_e, const float* __restrict__ top_p,
                            const float* __restrict__ b2, float* __restrict__ out) {
    int t = blockIdx.x;
    int e = top_e[t];
    float gv = top_p[t];
    const float* b = b2 + (size_t)e * ODIM;
    float* o = out + (size_t)t * ODIM;
    for (int i = threadIdx.x; i < ODIM; i += 256) o[i] = gv * b[i];
}

// ---------------- grouped GEMM, 2-phase double-buffered ----------------
// 128x128 tile, BK=32, 4 waves (2x2), wave tile 64x64 = 4x4 frags 16x16x32.
// LDS layout (both operands): [8 groups of 16 rows][4 kchunks][16][8] ushort
//   -> frag ds_read_b128 is lane-linear (lane L -> L*16B): conflict-free.
// A: global_load_lds, per-lane source row = group*16 + (lane&15), kchunk = lane>>4.
// B: 16 coalesced fp32 loads/thread -> cvt_pk -> 2x ds_write_b128 (lane-linear).
// Pipeline: issue next-iter A-DMA + B-loads BEFORE compute; one barrier/iter.
template<int LAYER>
__global__ __launch_bounds__(256, 4) void moe_gemm(
    const unsigned short* __restrict__ A, const float* __restrict__ B,
    const float* __restrict__ bias, const int* __restrict__ cnt,
    const int* __restrict__ offs, const int* __restrict__ perm,
    const float* __restrict__ gate_s, const int* __restrict__ tbl,
    const int* __restrict__ ntt, unsigned short* __restrict__ H,
    float* __restrict__ out) {

    constexpr int NT    = (LAYER == 1) ? HDIM : ODIM;
    constexpr int AST   = (LAYER == 1) ? DIM  : HDIM;
    constexpr int KFULL = (LAYER == 1) ? DIM  : HDIM;
    constexpr int KBLK  = (LAYER == 1) ? DIM  : HDIM / 4;
    constexpr int NITER = KBLK / 32;

    const int ent = blockIdx.y;
    if (ent >= ntt[0]) return;
    const int tt = tbl[ent];
    const int e  = tt >> 8;
    const int mt = tt & 255;
    const int ks = (LAYER == 1) ? 0 : blockIdx.z;
    const int ne = cnt[e];
    const int base = offs[e];
    const int n0 = blockIdx.x * 128;
    const int mlim = ne - mt * 128;
    const int kbase = ks * KBLK;

    __shared__ unsigned short As[2][4096];
    __shared__ unsigned short Bs[2][4096];

    const int tid = threadIdx.x;
    const int lane = tid & 63, w = tid >> 6;
    const int wr = w >> 1, wc = w & 1;
    const int g = lane >> 4, r = lane & 15;

    // A DMA source: wave w stages 16-row groups 2w, 2w+1
    const int rl0 = 2 * w * 16 + r;
    const int rl1 = rl0 + 16;
    const int cr0 = rl0 < mlim ? rl0 : mlim - 1;
    const int cr1 = rl1 < mlim ? rl1 : mlim - 1;
    const unsigned short* aS0 = A + (size_t)(base + mt * 128 + cr0) * AST + kbase + g * 8;
    const unsigned short* aS1 = A + (size_t)(base + mt * 128 + cr1) * AST + kbase + g * 8;
    const int aD0 = (2 * w) * 512;       // ushort offset in As[buf]
    const int aD1 = aD0 + 512;

    // B staging: thread owns col bn, 16 consecutive ks (half kh)
    const int bn = tid & 127;
    const int kh = tid >> 7;
    const float* bS = B + (size_t)e * KFULL * NT + (size_t)(kbase + kh * 16) * NT + n0 + bn;
    const int bD = (bn >> 4) * 512 + (kh * 2) * 128 + (bn & 15) * 8;

    f32x4 acc[4][4] = {};
    float bv[16];

#define STAGE(t_, buf_)                                                        \
    do {                                                                       \
        int koff_ = (t_) * 32;                                                 \
        gload_lds16(aS0 + koff_, &As[buf_][aD0]);                              \
        gload_lds16(aS1 + koff_, &As[buf_][aD1]);                              \
        const float* bp_ = bS + (size_t)koff_ * NT;                            \
        _Pragma("unroll")                                                      \
        for (int i_ = 0; i_ < 16; ++i_) bv[i_] = bp_[(size_t)i_ * NT];         \
    } while (0)

#define COMMITB(buf_)                                                          \
    do {                                                                       \
        uint4 q0_, q1_;                                                        \
        q0_.x = cvt_pk_bf16(bv[0],  bv[1]);  q0_.y = cvt_pk_bf16(bv[2],  bv[3]);  \
        q0_.z = cvt_pk_bf16(bv[4],  bv[5]);  q0_.w = cvt_pk_bf16(bv[6],  bv[7]);  \
        q1_.x = cvt_pk_bf16(bv[8],  bv[9]);  q1_.y = cvt_pk_bf16(bv[10], bv[11]); \
        q1_.z = cvt_pk_bf16(bv[12], bv[13]); q1_.w = cvt_pk_bf16(bv[14], bv[15]); \
        *(uint4*)&Bs[buf_][bD]       = q0_;                                    \
        *(uint4*)&Bs[buf_][bD + 128] = q1_;                                    \
    } while (0)

    STAGE(0, 0);
    COMMITB(0);
    __syncthreads();                       // drains vmcnt(0): A-DMA landed

    int cur = 0;
    for (int t = 0; t < NITER; ++t) {
        const bool last = (t == NITER - 1);
        if (!last) STAGE(t + 1, cur ^ 1);  // loads in flight during compute
        __builtin_amdgcn_sched_barrier(0); // keep load issue above compute
        bf16x8 af[4], bf[4];
#pragma unroll
        for (int m = 0; m < 4; ++m)
            af[m] = *(const bf16x8*)&As[cur][(wr * 4 + m) * 512 + lane * 8];
#pragma unroll
        for (int n = 0; n < 4; ++n)
            bf[n] = *(const bf16x8*)&Bs[cur][(wc * 4 + n) * 512 + lane * 8];
#pragma unroll
        for (int n = 0; n < 4; ++n)
#pragma unroll
            for (int m = 0; m < 4; ++m)
                acc[m][n] = __builtin_amdgcn_mfma_f32_16x16x32_bf16(af[m], bf[n], acc[m][n], 0, 0, 0);
        if (!last) {
            COMMITB(cur ^ 1);              // waits bv vmcnt (covers DMA, FIFO)
            __syncthreads();
            cur ^= 1;
        }
    }
#undef STAGE
#undef COMMITB

    // epilogue: C/D layout col = lane&15 (=r), row = 4*(lane>>4) (=4g) + reg
#pragma unroll
    for (int m = 0; m < 4; ++m) {
#pragma unroll
        for (int j = 0; j < 4; ++j) {
            int lrow = mt * 128 + wr * 64 + m * 16 + g * 4 + j;
            if (lrow < ne) {
                int slot = base + lrow;
#pragma unroll
                for (int n = 0; n < 4; ++n) {
                    int col = n0 + wc * 64 + n * 16 + r;
                    if constexpr (LAYER == 1) {
                        float v = acc[m][n][j] + bias[(size_t)e * NT + col];
                        v = fmaxf(v, 0.0f);
                        H[(size_t)slot * HDIM + col] = f2bf(v);
                    } else {
                        atomicAdd(&out[(size_t)perm[slot] * ODIM + col],
                                  gate_s[slot] * acc[m][n][j]);
                    }
                }
            }
        }
    }
}

// ---------------- launch ----------------
extern "C" void kernel_launch(void* const* d_in, const int* in_sizes, int n_in,
                              void* d_out, int out_size, void* d_ws, size_t ws_size,
                              hipStream_t stream) {
    const float* x  = (const float*)d_in[0];
    const float* Wg = (const float*)d_in[1];
    const float* bg = (const float*)d_in[2];
    const float* W1 = (const float*)d_in[3];
    const float* b1 = (const float*)d_in[4];
    const float* W2 = (const float*)d_in[5];
    const float* b2 = (const float*)d_in[6];
    float* out = (float*)d_out;

    char* ws = (char*)d_ws;
    int*   cnt    = (int*)(ws + 0);
    int*   offs   = (int*)(ws + 64);
    int*   ntt    = (int*)(ws + 96);
    int*   tbl    = (int*)(ws + 128);      // 40 ints
    int*   top_e  = (int*)(ws + 1024);
    int*   rnk    = (int*)(ws + 1024 + 16384);
    float* top_p  = (float*)(ws + 1024 + 2 * 16384);
    int*   perm   = (int*)(ws + 1024 + 3 * 16384);
    float* gate_s = (float*)(ws + 1024 + 4 * 16384);
    unsigned short* Xg = (unsigned short*)(ws + 82944);                           // 4096x768 bf16
    unsigned short* H  = (unsigned short*)(ws + 82944 + (size_t)N_TOK * DIM * 2); // 4096x7680 bf16
    // total ws: ~69.3 MB

    moe_init<<<1, 64, 0, stream>>>(cnt);
    moe_gating<<<N_TOK / 4, 256, 0, stream>>>(x, Wg, bg, cnt, top_e, rnk, top_p);
    moe_scan<<<1, 64, 0, stream>>>(cnt, offs, tbl, ntt);
    moe_mkperm<<<N_TOK / 256, 256, 0, stream>>>(top_e, rnk, top_p, offs, perm, gate_s);
    moe_gather<<<N_TOK, 256, 0, stream>>>(x, perm, Xg);
    moe_initout<<<N_TOK, 256, 0, stream>>>(top_e, top_p, b2, out);

    // x = n-tile (blocks sharing an A-panel sweep one expert's B panels),
    // y = tile-table entry, z = K-split (GEMM2 only)
    moe_gemm<1><<<dim3(HDIM / 128, MAXTILES, 1), 256, 0, stream>>>(
        Xg, W1, b1, cnt, offs, perm, gate_s, tbl, ntt, H, out);
    moe_gemm<2><<<dim3(ODIM / 128, MAXTILES, 4), 256, 0, stream>>>(
        H, W2, b2, cnt, offs, perm, gate_s, tbl, ntt, H, out);
}

// Round 4
// 409.210 us; speedup vs baseline: 3.2451x; 1.0077x over previous
//
#include <hip/hip_runtime.h>
#include <hip/hip_bf16.h>
#include <stdint.h>

// MoE top-1: gate -> group by expert -> tile table -> grouped bf16-MFMA GEMMs.
// GEMM: 128x128 tile, BK=32, counted-vmcnt pipeline (raw s_barrier, B-regs
// prefetched 2 K-steps deep, A via global_load_lds issued 1 step ahead).
#define N_TOK 4096
#define DIM   768
#define NE    8
#define HDIM  7680
#define ODIM  768
#define MAXTILES 40

typedef __bf16 bf16x8 __attribute__((ext_vector_type(8)));
typedef float f32x4 __attribute__((ext_vector_type(4)));

__device__ __forceinline__ unsigned short f2bf(float f) {
    union { float f; unsigned u; } v; v.f = f;
    return (unsigned short)((v.u + 0x7fffu + ((v.u >> 16) & 1u)) >> 16);
}

__device__ __forceinline__ unsigned cvt_pk_bf16(float lo, float hi) {
    unsigned r;
    asm("v_cvt_pk_bf16_f32 %0, %1, %2" : "=v"(r) : "v"(lo), "v"(hi));
    return r;
}

// async global->LDS, 16B/lane; LDS dest = wave-uniform base + lane*16
__device__ __forceinline__ void gload_lds16(const unsigned short* g, unsigned short* l) {
    __builtin_amdgcn_global_load_lds(
        (const __attribute__((address_space(1))) unsigned int*)g,
        (__attribute__((address_space(3))) unsigned int*)l, 16, 0, 0);
}

// ---------------- gating & prep (validated rounds 1-3) ----------------
__global__ void moe_gating(const float* __restrict__ x, const float* __restrict__ Wg,
                           const float* __restrict__ bg, int* __restrict__ cnt,
                           int* __restrict__ top_e, int* __restrict__ rnk,
                           float* __restrict__ top_p) {
    const int wid  = threadIdx.x >> 6;
    const int lane = threadIdx.x & 63;
    const int t = blockIdx.x * 4 + wid;
    double p[NE];
#pragma unroll
    for (int j = 0; j < NE; ++j) p[j] = 0.0;
    const float* xr  = x  + (size_t)t * DIM + lane * 12;
    const float* wr0 = Wg + lane * 12 * NE;
#pragma unroll
    for (int i = 0; i < 12; ++i) {
        double xv = (double)xr[i];
#pragma unroll
        for (int j = 0; j < NE; ++j) p[j] += xv * (double)wr0[i * NE + j];
    }
#pragma unroll
    for (int off = 32; off >= 1; off >>= 1)
#pragma unroll
        for (int j = 0; j < NE; ++j) p[j] += __shfl_xor(p[j], off, 64);
    if (lane == 0) {
        double l[NE];
#pragma unroll
        for (int j = 0; j < NE; ++j) l[j] = p[j] + (double)bg[j];
        int be = 0; double bl = l[0];
#pragma unroll
        for (int j = 1; j < NE; ++j) if (l[j] > bl) { bl = l[j]; be = j; }
        double s = 0.0;
#pragma unroll
        for (int j = 0; j < NE; ++j) s += exp(l[j] - bl);
        int rk = atomicAdd(&cnt[be], 1);
        top_e[t] = be; rnk[t] = rk; top_p[t] = (float)(1.0 / s);
    }
}

__global__ void moe_init(int* cnt) { if (threadIdx.x < NE) cnt[threadIdx.x] = 0; }

__global__ void moe_scan(const int* __restrict__ cnt, int* __restrict__ offs,
                         int* __restrict__ tbl, int* __restrict__ ntt) {
    if (threadIdx.x == 0) {
        int s = 0, nt = 0;
        for (int e = 0; e < NE; ++e) {
            offs[e] = s;
            int m = (cnt[e] + 127) >> 7;
            for (int i = 0; i < m; ++i) tbl[nt++] = (e << 8) | i;
            s += cnt[e];
        }
        ntt[0] = nt;
    }
}

__global__ void moe_mkperm(const int* __restrict__ top_e, const int* __restrict__ rnk,
                           const float* __restrict__ top_p, const int* __restrict__ offs,
                           int* __restrict__ perm, float* __restrict__ gate_s) {
    int t = blockIdx.x * 256 + threadIdx.x;
    int e = top_e[t];
    int slot = offs[e] + rnk[t];
    perm[slot] = t;
    gate_s[slot] = top_p[t];
}

__global__ void moe_gather(const float* __restrict__ x, const int* __restrict__ perm,
                           unsigned short* __restrict__ Xg) {
    int slot = blockIdx.x;
    int t = perm[slot];
    const float* src = x + (size_t)t * DIM;
    unsigned short* dst = Xg + (size_t)slot * DIM;
    for (int i = threadIdx.x; i < DIM; i += 256) dst[i] = f2bf(src[i]);
}

__global__ void moe_initout(const int* __restrict__ top_e, const float* __restrict__ top_p,
                            const float* __restrict__ b2, float* __restrict__ out) {
    int t = blockIdx.x;
    int e = top_e[t];
    float gv = top_p[t];
    const float* b = b2 + (size_t)e * ODIM;
    float* o = out + (size_t)t * ODIM;
    for (int i = threadIdx.x; i < ODIM; i += 256) o[i] = gv * b[i];
}

// ---------------- grouped GEMM, counted-vmcnt 2-deep pipeline ----------------
// LDS layout both operands: [8 groups of 16 rows][4 kchunks][16][8] ushort
//   -> all frag ds_read_b128 lane-linear: conflict-free (verified r3: 0 conflicts).
// Steady-state iter t: ds_read frags(cur) | DMA A(t+1 -> cur^1) | load B(t+2)->regs
//   | lgkmcnt(0) | 64 MFMA | vmcnt(16)  (B(t+1)+DMA(t+1) done, B(t+2) in flight)
//   | cvt+ds_write B(t+1)->cur^1 | lgkmcnt(0) | s_barrier.
template<int LAYER>
__global__ __launch_bounds__(256, 3) void moe_gemm(
    const unsigned short* __restrict__ A, const float* __restrict__ B,
    const float* __restrict__ bias, const int* __restrict__ cnt,
    const int* __restrict__ offs, const int* __restrict__ perm,
    const float* __restrict__ gate_s, const int* __restrict__ tbl,
    const int* __restrict__ ntt, unsigned short* __restrict__ H,
    float* __restrict__ out) {

    constexpr int NT    = (LAYER == 1) ? HDIM : ODIM;
    constexpr int AST   = (LAYER == 1) ? DIM  : HDIM;
    constexpr int KFULL = (LAYER == 1) ? DIM  : HDIM;
    constexpr int KBLK  = (LAYER == 1) ? DIM  : HDIM / 4;
    constexpr int NITER = KBLK / 32;              // 24 / 60 (even, >=4)

    const int ent = blockIdx.x;                   // m fastest: same-slice B readers adjacent
    if (ent >= ntt[0]) return;
    const int tt = tbl[ent];
    const int e  = tt >> 8;
    const int mt = tt & 255;
    const int ks = (LAYER == 1) ? 0 : blockIdx.z;
    const int ne = cnt[e];
    const int base = offs[e];
    const int n0 = blockIdx.y * 128;
    const int mlim = ne - mt * 128;
    const int kbase = ks * KBLK;

    __shared__ unsigned short As[2][4096];
    __shared__ unsigned short Bs[2][4096];

    const int tid = threadIdx.x;
    const int lane = tid & 63, w = tid >> 6;
    const int wr = w >> 1, wc = w & 1;
    const int g = lane >> 4, r = lane & 15;

    // A DMA: wave w stages 16-row groups 2w, 2w+1 (rows clamped for partial tiles)
    const int rl0 = 2 * w * 16 + r;
    const int rl1 = rl0 + 16;
    const int cr0 = rl0 < mlim ? rl0 : mlim - 1;
    const int cr1 = rl1 < mlim ? rl1 : mlim - 1;
    const unsigned short* aS0 = A + (size_t)(base + mt * 128 + cr0) * AST + kbase + g * 8;
    const unsigned short* aS1 = A + (size_t)(base + mt * 128 + cr1) * AST + kbase + g * 8;
    const int aD0 = (2 * w) * 512;
    const int aD1 = aD0 + 512;

    // B staging: thread owns col bn, 16 consecutive ks (half kh)
    const int bn = tid & 127;
    const int kh = tid >> 7;
    const float* bS = B + (size_t)e * KFULL * NT + (size_t)(kbase + kh * 16) * NT + n0 + bn;
    const int bD = (bn >> 4) * 512 + (kh * 2) * 128 + (bn & 15) * 8;

    f32x4 acc[4][4] = {};
    float bvA[16], bvB[16];

#define FENCE __builtin_amdgcn_sched_barrier(0)

#define LOADB(dst_, t_)                                                        \
    do { const float* bp_ = bS + (size_t)((t_) * 32) * NT;                     \
        _Pragma("unroll")                                                      \
        for (int i_ = 0; i_ < 16; ++i_) dst_[i_] = bp_[(size_t)i_ * NT];       \
    } while (0)

#define DMA_A(t_, buf_)                                                        \
    do { gload_lds16(aS0 + (t_) * 32, &As[buf_][aD0]);                         \
         gload_lds16(aS1 + (t_) * 32, &As[buf_][aD1]); } while (0)

#define COMMITB(src_, buf_)                                                    \
    do { uint4 q0_, q1_;                                                       \
        q0_.x = cvt_pk_bf16(src_[0],  src_[1]);  q0_.y = cvt_pk_bf16(src_[2],  src_[3]);  \
        q0_.z = cvt_pk_bf16(src_[4],  src_[5]);  q0_.w = cvt_pk_bf16(src_[6],  src_[7]);  \
        q1_.x = cvt_pk_bf16(src_[8],  src_[9]);  q1_.y = cvt_pk_bf16(src_[10], src_[11]); \
        q1_.z = cvt_pk_bf16(src_[12], src_[13]); q1_.w = cvt_pk_bf16(src_[14], src_[15]); \
        *(uint4*)&Bs[buf_][bD]       = q0_;                                    \
        *(uint4*)&Bs[buf_][bD + 128] = q1_;                                    \
    } while (0)

// MODE 2: steady (DMA t+1, load B t+2, wait vmcnt(16), commit, barrier)
// MODE 1: t==NITER-2 (DMA t+1, no loads, wait vmcnt(0), commit, barrier)
// MODE 0: t==NITER-1 (compute only)
#define BODY(t_, cur_, LDst_, CMsrc_, MODE_)                                   \
    do {                                                                       \
        bf16x8 af_[4], bf_[4];                                                 \
        _Pragma("unroll")                                                      \
        for (int m_ = 0; m_ < 4; ++m_)                                         \
            af_[m_] = *(const bf16x8*)&As[cur_][(wr * 4 + m_) * 512 + lane * 8]; \
        _Pragma("unroll")                                                      \
        for (int n_ = 0; n_ < 4; ++n_)                                         \
            bf_[n_] = *(const bf16x8*)&Bs[cur_][(wc * 4 + n_) * 512 + lane * 8]; \
        FENCE;                                                                 \
        if (MODE_ >= 1) DMA_A((t_) + 1, (cur_) ^ 1);                           \
        FENCE;                                                                 \
        if (MODE_ == 2) LOADB(LDst_, (t_) + 2);                                \
        asm volatile("s_waitcnt lgkmcnt(0)" ::: "memory");                     \
        FENCE;                                                                 \
        _Pragma("unroll")                                                      \
        for (int n_ = 0; n_ < 4; ++n_)                                         \
            _Pragma("unroll")                                                  \
            for (int m_ = 0; m_ < 4; ++m_)                                     \
                acc[m_][n_] = __builtin_amdgcn_mfma_f32_16x16x32_bf16(         \
                    af_[m_], bf_[n_], acc[m_][n_], 0, 0, 0);                   \
        FENCE;                                                                 \
        if (MODE_ == 2) { asm volatile("s_waitcnt vmcnt(16)" ::: "memory"); }  \
        else if (MODE_ == 1) { asm volatile("s_waitcnt vmcnt(0)" ::: "memory"); } \
        if (MODE_ >= 1) {                                                      \
            COMMITB(CMsrc_, (cur_) ^ 1);                                       \
            asm volatile("s_waitcnt lgkmcnt(0)" ::: "memory");                 \
            __builtin_amdgcn_s_barrier();                                      \
            FENCE;                                                             \
        }                                                                      \
    } while (0)

    // prologue: B(0)->bvA, DMA(0)->buf0, B(1)->bvB; commit B(0)
    LOADB(bvA, 0);
    FENCE;
    DMA_A(0, 0);
    FENCE;
    LOADB(bvB, 1);
    asm volatile("s_waitcnt vmcnt(16)" ::: "memory");   // B(0)+DMA(0) done
    FENCE;
    COMMITB(bvA, 0);
    asm volatile("s_waitcnt lgkmcnt(0)" ::: "memory");
    __builtin_amdgcn_s_barrier();
    FENCE;

#pragma unroll 1
    for (int t = 0; t + 4 <= NITER; t += 2) {
        BODY(t,     0, bvA, bvB, 2);
        BODY(t + 1, 1, bvB, bvA, 2);
    }
    BODY(NITER - 2, 0, bvA, bvB, 1);
    BODY(NITER - 1, 1, bvB, bvA, 0);

#undef BODY
#undef COMMITB
#undef DMA_A
#undef LOADB
#undef FENCE

    // epilogue: C/D layout col = lane&15 (=r), row = 4*(lane>>4) (=4g) + reg
#pragma unroll
    for (int m = 0; m < 4; ++m) {
#pragma unroll
        for (int j = 0; j < 4; ++j) {
            int lrow = mt * 128 + wr * 64 + m * 16 + g * 4 + j;
            if (lrow < ne) {
                int slot = base + lrow;
#pragma unroll
                for (int n = 0; n < 4; ++n) {
                    int col = n0 + wc * 64 + n * 16 + r;
                    if constexpr (LAYER == 1) {
                        float v = acc[m][n][j] + bias[(size_t)e * NT + col];
                        v = fmaxf(v, 0.0f);
                        H[(size_t)slot * HDIM + col] = f2bf(v);
                    } else {
                        atomicAdd(&out[(size_t)perm[slot] * ODIM + col],
                                  gate_s[slot] * acc[m][n][j]);
                    }
                }
            }
        }
    }
}

// ---------------- launch ----------------
extern "C" void kernel_launch(void* const* d_in, const int* in_sizes, int n_in,
                              void* d_out, int out_size, void* d_ws, size_t ws_size,
                              hipStream_t stream) {
    const float* x  = (const float*)d_in[0];
    const float* Wg = (const float*)d_in[1];
    const float* bg = (const float*)d_in[2];
    const float* W1 = (const float*)d_in[3];
    const float* b1 = (const float*)d_in[4];
    const float* W2 = (const float*)d_in[5];
    const float* b2 = (const float*)d_in[6];
    float* out = (float*)d_out;

    char* ws = (char*)d_ws;
    int*   cnt    = (int*)(ws + 0);
    int*   offs   = (int*)(ws + 64);
    int*   ntt    = (int*)(ws + 96);
    int*   tbl    = (int*)(ws + 128);
    int*   top_e  = (int*)(ws + 1024);
    int*   rnk    = (int*)(ws + 1024 + 16384);
    float* top_p  = (float*)(ws + 1024 + 2 * 16384);
    int*   perm   = (int*)(ws + 1024 + 3 * 16384);
    float* gate_s = (float*)(ws + 1024 + 4 * 16384);
    unsigned short* Xg = (unsigned short*)(ws + 82944);
    unsigned short* H  = (unsigned short*)(ws + 82944 + (size_t)N_TOK * DIM * 2);

    moe_init<<<1, 64, 0, stream>>>(cnt);
    moe_gating<<<N_TOK / 4, 256, 0, stream>>>(x, Wg, bg, cnt, top_e, rnk, top_p);
    moe_scan<<<1, 64, 0, stream>>>(cnt, offs, tbl, ntt);
    moe_mkperm<<<N_TOK / 256, 256, 0, stream>>>(top_e, rnk, top_p, offs, perm, gate_s);
    moe_gather<<<N_TOK, 256, 0, stream>>>(x, perm, Xg);
    moe_initout<<<N_TOK, 256, 0, stream>>>(top_e, top_p, b2, out);

    // x = tile entry (m-tiles of one expert adjacent -> weight-slice reuse),
    // y = n-tile, z = K-split (GEMM2)
    moe_gemm<1><<<dim3(MAXTILES, HDIM / 128, 1), 256, 0, stream>>>(
        Xg, W1, b1, cnt, offs, perm, gate_s, tbl, ntt, H, out);
    moe_gemm<2><<<dim3(MAXTILES, ODIM / 128, 4), 256, 0, stream>>>(
        H, W2, b2, cnt, offs, perm, gate_s, tbl, ntt, H, out);
}